// Round 20
// baseline (288.772 us; speedup 1.0000x reference)
//
#include <hip/hip_runtime.h>

typedef _Float16 f16;
typedef __attribute__((ext_vector_type(2))) _Float16 f16x2;
typedef __attribute__((ext_vector_type(8))) _Float16 f16x8;
typedef __attribute__((ext_vector_type(4))) float f32x4;
typedef __attribute__((ext_vector_type(2))) float f32x2;

#define BSH 9   // 512 nodes per bucket

// ---------------- fused first kernel: weight conv + zeroing | bucket count | x->fp16 ----------------
__global__ __launch_bounds__(256) void k_wconv(const float* __restrict__ w1, const float* __restrict__ w2,
                                               const float* __restrict__ w3, f16* __restrict__ whi,
                                               f16* __restrict__ wlo, const int* __restrict__ col,
                                               int* __restrict__ bcnt, int* __restrict__ gcnt,
                                               float* __restrict__ gsum, const float* __restrict__ x,
                                               f16* __restrict__ xh, int e, int nx, int nwg_e) {
    int t = threadIdx.x;
    if (blockIdx.x < 192) {
        int tid = blockIdx.x * 256 + t;
        if (tid < 64) gcnt[tid] = 0;
        else if (tid < 64 + 8192) gsum[tid - 64] = 0.f;

        int wsel = blockIdx.x >> 6;
        const float* w = (wsel == 0) ? w1 : (wsel == 1) ? w2 : w3;
        int fi = (blockIdx.x & 63) * 256 + t;   // 0..16383
        int j  = fi & 7;
        int l  = (fi >> 3) & 63;
        int ks = (fi >> 9) & 3;
        int ct = fi >> 11;
        int k = ks * 32 + (l >> 4) * 8 + j;
        int c = ct * 16 + (l & 15);
        float xv = w[k * 128 + c];
        f16 hi = (f16)xv;
        f16 lo = (f16)(xv - (float)hi);
        whi[wsel * 16384 + fi] = hi;
        wlo[wsel * 16384 + fi] = lo;
    } else if (blockIdx.x < 192 + nwg_e) {
        __shared__ int h[256];
        h[t] = 0;
        __syncthreads();
        int bid = blockIdx.x - 192;
        int i0 = bid * 4096;
        int i1 = min(i0 + 4096, e);
        for (int i = i0 + t; i < i1; i += 256) atomicAdd(&h[col[i] >> BSH], 1);
        __syncthreads();
        if (h[t]) atomicAdd(&bcnt[t], h[t]);
    } else {
        long bid = blockIdx.x - 192 - nwg_e;
        long i = bid * 2048 + (long)t * 8;
        if (i + 8 <= nx) {
            float4 a = ((const float4*)(x + i))[0];
            float4 b = ((const float4*)(x + i))[1];
            f16x8 v;
            v[0] = (f16)a.x; v[1] = (f16)a.y; v[2] = (f16)a.z; v[3] = (f16)a.w;
            v[4] = (f16)b.x; v[5] = (f16)b.y; v[6] = (f16)b.z; v[7] = (f16)b.w;
            *(f16x8*)(xh + i) = v;
        } else {
            for (; i < nx; i++) xh[i] = (f16)x[i];
        }
    }
}

// ---------------- bucket scan ----------------
__global__ __launch_bounds__(256) void k_bscan(const int* __restrict__ bcnt, int* __restrict__ bbase,
                                               int* __restrict__ bcur, int* __restrict__ colptr, int e, int n) {
    __shared__ int s[256];
    int t = threadIdx.x;
    int v = bcnt[t];
    s[t] = v;
    __syncthreads();
    for (int off = 1; off < 256; off <<= 1) {
        int mine = s[t];
        int add  = (t >= off) ? s[t - off] : 0;
        __syncthreads();
        s[t] = mine + add;
        __syncthreads();
    }
    int incl = s[t];
    bbase[t + 1] = incl;
    bcur[t] = incl - v;
    if (t == 0) {
        bbase[0] = 0;
        colptr[n] = e;
    }
}

// ---------------- bucket partition ----------------
__global__ __launch_bounds__(256) void k_part(const int* __restrict__ row, const int* __restrict__ col,
                                              int* __restrict__ bcur, int* __restrict__ ebuck, int e) {
    __shared__ int hist[256];
    __shared__ int excl[256];
    __shared__ int rbase[256];
    __shared__ int2 stage[4096];
    int t = threadIdx.x;
    int wgbase = blockIdx.x * 4096;
    int total = min(4096, e - wgbase);

    hist[t] = 0;
    __syncthreads();

    int  mypk[16];
    int  myb[16];
    int  myrank[16];
    #pragma unroll
    for (int k = 0; k < 16; k++) {
        int i = wgbase + k * 256 + t;
        int pk = 0, b = 0, rnk = 0;
        if (i < e) {
            int r = row[i];
            int c = col[i];
            b = c >> BSH;
            pk = (r << BSH) | (c & ((1 << BSH) - 1));
            rnk = atomicAdd(&hist[b], 1);
        }
        mypk[k] = pk;
        myb[k] = b;
        myrank[k] = rnk;
    }
    __syncthreads();

    excl[t] = hist[t];
    __syncthreads();
    for (int off = 1; off < 256; off <<= 1) {
        int mine = excl[t];
        int add  = (t >= off) ? excl[t - off] : 0;
        __syncthreads();
        excl[t] = mine + add;
        __syncthreads();
    }
    excl[t] -= hist[t];
    rbase[t] = (hist[t] > 0) ? atomicAdd(&bcur[t], hist[t]) : 0;
    __syncthreads();

    #pragma unroll
    for (int k = 0; k < 16; k++) {
        int i = wgbase + k * 256 + t;
        if (i < e) stage[excl[myb[k]] + myrank[k]] = make_int2(mypk[k], myb[k]);
    }
    __syncthreads();

    for (int j = t; j < total; j += 256) {
        int2 pe = stage[j];
        int b = pe.y;
        ebuck[rbase[b] + (j - excl[b])] = pe.x;
    }
}

// ---------------- per-bucket: histogram + scan -> colptr/dinv, scatter esrc via LDS cursors ----------------
__global__ __launch_bounds__(256) void k_nodefill(const int* __restrict__ ebuck, const int* __restrict__ bbase,
                                                  int* __restrict__ colptr, float* __restrict__ dinv,
                                                  int* __restrict__ esrc, int n) {
    __shared__ int h[512];
    __shared__ int s[256];
    __shared__ int cur[512];
    int b = blockIdx.x;
    int t = threadIdx.x;
    h[t] = 0;
    h[t + 256] = 0;
    __syncthreads();
    int e_lo = bbase[b], e_hi = bbase[b + 1];
    for (int i = e_lo + t; i < e_hi; i += 256) atomicAdd(&h[ebuck[i] & 511], 1);
    __syncthreads();
    int a0 = h[2 * t], a1 = h[2 * t + 1];
    s[t] = a0 + a1;
    __syncthreads();
    for (int off = 1; off < 256; off <<= 1) {
        int mine = s[t];
        int add  = (t >= off) ? s[t - off] : 0;
        __syncthreads();
        s[t] = mine + add;
        __syncthreads();
    }
    int sexcl = s[t] - (a0 + a1);
    int g0 = (b << BSH) + 2 * t;
    int g1 = g0 + 1;
    int cp0 = e_lo + sexcl;
    int cp1 = cp0 + a0;
    if (g0 < n) {
        colptr[g0] = cp0;
        dinv[g0] = rsqrtf((float)(a0 + 1));
    }
    if (g1 < n) {
        colptr[g1] = cp1;
        dinv[g1] = rsqrtf((float)(a1 + 1));
    }
    cur[2 * t]     = cp0;
    cur[2 * t + 1] = cp1;
    __syncthreads();
    for (int i = e_lo + t; i < e_hi; i += 256) {
        int pk = ebuck[i];
        int pos = atomicAdd(&cur[pk & 511], 1);
        esrc[pos] = pk >> BSH;
    }
}

__device__ __forceinline__ unsigned char f32_to_fp8(float v) {
    int pk = __builtin_amdgcn_cvt_pk_fp8_f32(v, v, 0, 0);
    return (unsigned char)(pk & 0xff);
}

// ---------------- GEMM (fp16 input, all 3 layers, 128-row blocks): A[r] = fp8(dinv[r]*(in[r]@W + b)) ----------------
// Wave (wr,wc) computes a 64x64 quadrant: acc[4][4], 128 MFMAs/wave. LDS-staged fp8 epilogue.
__global__ __launch_bounds__(256) void k_gemm_f16in(const f16* __restrict__ in, const f16* __restrict__ whi,
                                                    const f16* __restrict__ wlo, const float* __restrict__ bias,
                                                    const float* __restrict__ dinv, unsigned char* __restrict__ out,
                                                    int n) {
    __shared__ unsigned char ot[128 * 128];
    int lane = threadIdx.x & 63;
    int wid  = threadIdx.x >> 6;
    int wr = wid >> 1, wc = wid & 1;
    int rbase0 = blockIdx.x * 128;
    int rbase = rbase0 + wr * 64;
    int rowA = lane & 15;
    int kg   = lane >> 4;

    f32x4 acc[4][4];
    #pragma unroll
    for (int i = 0; i < 4; i++)
        #pragma unroll
        for (int j = 0; j < 4; j++) acc[i][j] = (f32x4){0.f, 0.f, 0.f, 0.f};

    #pragma unroll
    for (int ks = 0; ks < 4; ks++) {
        f16x8 ah[4];
        #pragma unroll
        for (int rt = 0; rt < 4; rt++) {
            int r = rbase + rt * 16 + rowA;
            int k0 = ks * 32 + kg * 8;
            f16x8 v = {};
            if (r < n) v = *(const f16x8*)(in + (size_t)r * 128 + k0);
            ah[rt] = v;
        }
        f16x8 bh[4], bl[4];
        #pragma unroll
        for (int ct = 0; ct < 4; ct++) {
            int g = ((wc * 4 + ct) * 4 + ks);
            size_t idx = (size_t)(g * 64 + lane) * 8;
            bh[ct] = *(const f16x8*)(whi + idx);
            bl[ct] = *(const f16x8*)(wlo + idx);
        }
        #pragma unroll
        for (int rt = 0; rt < 4; rt++)
            #pragma unroll
            for (int ct = 0; ct < 4; ct++) {
                acc[rt][ct] = __builtin_amdgcn_mfma_f32_16x16x32_f16(ah[rt], bl[ct], acc[rt][ct], 0, 0, 0);
                acc[rt][ct] = __builtin_amdgcn_mfma_f32_16x16x32_f16(ah[rt], bh[ct], acc[rt][ct], 0, 0, 0);
            }
    }

    int cl = lane & 15;
    int rq = lane >> 4;
    #pragma unroll
    for (int rt = 0; rt < 4; rt++) {
        #pragma unroll
        for (int ct = 0; ct < 4; ct++) {
            int c = wc * 64 + ct * 16 + cl;
            float bv = bias[c];
            #pragma unroll
            for (int reg = 0; reg < 4; reg++) {
                int rl = wr * 64 + rt * 16 + rq * 4 + reg;
                int r = rbase0 + rl;
                if (r < n) {
                    float dv = dinv[r];
                    ot[rl * 128 + c] = f32_to_fp8(dv * (acc[rt][ct][reg] + bv));
                }
            }
        }
    }
    __syncthreads();

    int rows = min(128, n - rbase0);
    uint4* dst = (uint4*)(out + (size_t)rbase0 * 128);
    const uint4* src = (const uint4*)ot;
    for (int idx = threadIdx.x; idx < rows * 8; idx += 256) dst[idx] = src[idx];
}

// ---------------- Aggregation v6-fp8: 2 nodes/wave, 16 B/lane uint4 loads, 8-slot stepping ----------------
__global__ __launch_bounds__(256) void k_agg(const unsigned char* __restrict__ A, const int* __restrict__ colptr,
                                             const int* __restrict__ esrc, const float* __restrict__ dinv,
                                             f16* __restrict__ B, int n) {
    int lane = threadIdx.x & 63;
    int half = lane >> 5;
    int l = lane & 31;
    int eg = l >> 3;     // 0..3
    int cs = l & 7;      // 0..7
    int v = blockIdx.x * 8 + (threadIdx.x >> 6) * 2 + half;
    const uint4* __restrict__ A16 = (const uint4*)A;

    int p0 = 0, total = 0;
    if (v < n) {
        p0 = colptr[v];
        int p1 = colptr[v + 1];
        total = p1 - p0 + 1;
    }

    f32x2 acc2[8];
    #pragma unroll
    for (int j = 0; j < 8; j++) acc2[j] = (f32x2){0.f, 0.f};

    for (int base = 0; base < total; base += 8) {
        int q0 = base + eg;
        int q1 = base + 4 + eg;
        int s0 = (q0 < total - 1) ? esrc[p0 + q0] : v;
        int s1 = (q1 < total - 1) ? esrc[p0 + q1] : v;
        uint4 r0 = A16[(size_t)s0 * 8 + cs];
        uint4 r1 = A16[(size_t)s1 * 8 + cs];
        float m0 = (q0 < total) ? 1.f : 0.f;
        float m1 = (q1 < total) ? 1.f : 0.f;
        f32x2 m0v = (f32x2){m0, m0};
        f32x2 m1v = (f32x2){m1, m1};
        acc2[0] = __builtin_amdgcn_cvt_pk_f32_fp8((int)r0.x, false) * m0v + acc2[0];
        acc2[1] = __builtin_amdgcn_cvt_pk_f32_fp8((int)r0.x, true)  * m0v + acc2[1];
        acc2[2] = __builtin_amdgcn_cvt_pk_f32_fp8((int)r0.y, false) * m0v + acc2[2];
        acc2[3] = __builtin_amdgcn_cvt_pk_f32_fp8((int)r0.y, true)  * m0v + acc2[3];
        acc2[4] = __builtin_amdgcn_cvt_pk_f32_fp8((int)r0.z, false) * m0v + acc2[4];
        acc2[5] = __builtin_amdgcn_cvt_pk_f32_fp8((int)r0.z, true)  * m0v + acc2[5];
        acc2[6] = __builtin_amdgcn_cvt_pk_f32_fp8((int)r0.w, false) * m0v + acc2[6];
        acc2[7] = __builtin_amdgcn_cvt_pk_f32_fp8((int)r0.w, true)  * m0v + acc2[7];
        acc2[0] = __builtin_amdgcn_cvt_pk_f32_fp8((int)r1.x, false) * m1v + acc2[0];
        acc2[1] = __builtin_amdgcn_cvt_pk_f32_fp8((int)r1.x, true)  * m1v + acc2[1];
        acc2[2] = __builtin_amdgcn_cvt_pk_f32_fp8((int)r1.y, false) * m1v + acc2[2];
        acc2[3] = __builtin_amdgcn_cvt_pk_f32_fp8((int)r1.y, true)  * m1v + acc2[3];
        acc2[4] = __builtin_amdgcn_cvt_pk_f32_fp8((int)r1.z, false) * m1v + acc2[4];
        acc2[5] = __builtin_amdgcn_cvt_pk_f32_fp8((int)r1.z, true)  * m1v + acc2[5];
        acc2[6] = __builtin_amdgcn_cvt_pk_f32_fp8((int)r1.w, false) * m1v + acc2[6];
        acc2[7] = __builtin_amdgcn_cvt_pk_f32_fp8((int)r1.w, true)  * m1v + acc2[7];
    }

    float accf[16];
    #pragma unroll
    for (int j = 0; j < 8; j++) {
        #pragma unroll
        for (int h = 0; h < 2; h++) {
            float a = acc2[j][h];
            a += __shfl_xor(a, 8, 64);
            a += __shfl_xor(a, 16, 64);
            accf[2 * j + h] = a;
        }
    }

    if (v < n && l < 8) {
        float d = dinv[v];
        f16x8 o0, o1;
        #pragma unroll
        for (int j = 0; j < 8; j++) {
            o0[j] = (f16)fmaxf(d * accf[j], 0.f);
            o1[j] = (f16)fmaxf(d * accf[8 + j], 0.f);
        }
        f16x8* Bp = (f16x8*)(B + (size_t)v * 128 + cs * 16);
        Bp[0] = o0;
        Bp[1] = o1;
    }
}

// ---------------- Pooling (batch is sorted), B fp16, f16x2 per lane ----------------
__global__ __launch_bounds__(64) void k_pool(const f16* __restrict__ B, const int* __restrict__ batch,
                                             float* __restrict__ gsum, int* __restrict__ gcnt, int n) {
    int c = threadIdx.x;
    int base = blockIdx.x * 64;
    if (base >= n) return;
    int end = min(base + 64, n);
    int curg = batch[base];
    const f16x2* __restrict__ B2 = (const f16x2*)B;
    float ax = 0.f, ay = 0.f;
    int cnt = 0;
    for (int i = base; i < end; i++) {
        int g = batch[i];
        if (g != curg) {
            atomicAdd(&gsum[curg * 128 + 2 * c], ax);
            atomicAdd(&gsum[curg * 128 + 2 * c + 1], ay);
            if (c == 0) atomicAdd(&gcnt[curg], cnt);
            ax = ay = 0.f; cnt = 0; curg = g;
        }
        f16x2 v = B2[(size_t)i * 64 + c];
        ax += (float)v.x;
        ay += (float)v.y;
        cnt++;
    }
    atomicAdd(&gsum[curg * 128 + 2 * c], ax);
    atomicAdd(&gsum[curg * 128 + 2 * c + 1], ay);
    if (c == 0) atomicAdd(&gcnt[curg], cnt);
}

// ---------------- Head ----------------
__global__ __launch_bounds__(128) void k_head(const float* __restrict__ gsum, const int* __restrict__ gcnt,
                                              const float* __restrict__ hw1, const float* __restrict__ hb1,
                                              const float* __restrict__ hw2, const float* __restrict__ hb2,
                                              float* __restrict__ out) {
    __shared__ float mean[128];
    __shared__ float red[128];
    int g = blockIdx.x;
    int c = threadIdx.x;
    float cntf = fmaxf((float)gcnt[g], 1.0f);
    mean[c] = gsum[g * 128 + c] / cntf;
    __syncthreads();
    float h = hb1[c];
    for (int k = 0; k < 128; k++) h = fmaf(mean[k], hw1[k * 128 + c], h);
    h = fmaxf(h, 0.f);
    red[c] = h * hw2[c];
    __syncthreads();
    for (int s = 64; s > 0; s >>= 1) {
        if (c < s) red[c] += red[c + s];
        __syncthreads();
    }
    if (c == 0) out[g] = red[0] + hb2[0];
}

// ---------------- launch ----------------
extern "C" void kernel_launch(void* const* d_in, const int* in_sizes, int n_in,
                              void* d_out, int out_size, void* d_ws, size_t ws_size,
                              hipStream_t stream) {
    const float* x   = (const float*)d_in[0];
    const int*  edge = (const int*)d_in[1];
    const int*  batch= (const int*)d_in[2];
    const float* w1  = (const float*)d_in[3];
    const float* b1  = (const float*)d_in[4];
    const float* w2  = (const float*)d_in[5];
    const float* b2  = (const float*)d_in[6];
    const float* w3  = (const float*)d_in[7];
    const float* b3  = (const float*)d_in[8];
    const float* hw1 = (const float*)d_in[9];
    const float* hb1 = (const float*)d_in[10];
    const float* hw2 = (const float*)d_in[11];
    const float* hb2 = (const float*)d_in[12];
    float* out = (float*)d_out;

    const int n = in_sizes[0] / 128;
    const int e = in_sizes[1] / 2;
    const int* row = edge;
    const int* col = edge + e;

    char* wsb = (char*)d_ws;
    size_t off = 0;
    auto alloc = [&](size_t bytes) -> void* {
        void* p = wsb + off;
        off = (off + bytes + 511) & ~size_t(511);
        return p;
    };
    unsigned char* A = (unsigned char*)alloc((size_t)n * 128);   // fp8 activations (gemm out, gathered)
    f16*   Bb     = (f16*)  alloc((size_t)n * 128 * 2);          // fp16 activations (agg out)
    f16*   xh     = (f16*)  alloc((size_t)n * 128 * 2);          // fp16 copy of x
    int*   ebuck  = (int*)  alloc((size_t)e * 4);
    float* dinv   = (float*)alloc((size_t)n * 4);
    int*   colptr = (int*)  alloc((size_t)(n + 1) * 4);
    int*   bcnt   = (int*)  alloc(1024);
    int*   bbase  = (int*)  alloc(1028 + 508);
    int*   bcur   = (int*)  alloc(1024);
    int*   esrc   = (int*)  alloc((size_t)e * 4);
    float* gsum   = (float*)alloc(64 * 128 * 4);
    int*   gcnt   = (int*)  alloc(64 * 4);
    f16*   whi    = (f16*)  alloc(3 * 16384 * 2);
    f16*   wlo    = (f16*)  alloc(3 * 16384 * 2);

    hipMemsetAsync(bcnt, 0, 1024, stream);

    int nwg_e = (e + 4095) / 4096;
    int nwg_x = (n * 128 + 2047) / 2048;
    int nbk = (n + (1 << BSH) - 1) >> BSH;

    // fused: weight conv + zeroing | bucket count | x->fp16
    k_wconv<<<192 + nwg_e + nwg_x, 256, 0, stream>>>(w1, w2, w3, whi, wlo, col, bcnt, gcnt, gsum,
                                                     x, xh, e, n * 128, nwg_e);

    k_bscan<<<1, 256, 0, stream>>>(bcnt, bbase, bcur, colptr, e, n);
    k_part<<<nwg_e, 256, 0, stream>>>(row, col, bcur, ebuck, e);
    k_nodefill<<<nbk, 256, 0, stream>>>(ebuck, bbase, colptr, dinv, esrc, n);

    int gb = (n + 127) / 128;
    int ab = (n + 7) / 8;
    k_gemm_f16in<<<gb, 256, 0, stream>>>(xh, whi,             wlo,             b1, dinv, A, n);
    k_agg <<<ab, 256, 0, stream>>>(A, colptr, esrc, dinv, Bb, n);
    k_gemm_f16in<<<gb, 256, 0, stream>>>(Bb, whi + 16384,     wlo + 16384,     b2, dinv, A, n);
    k_agg <<<ab, 256, 0, stream>>>(A, colptr, esrc, dinv, Bb, n);
    k_gemm_f16in<<<gb, 256, 0, stream>>>(Bb, whi + 2 * 16384, wlo + 2 * 16384, b3, dinv, A, n);
    k_agg <<<ab, 256, 0, stream>>>(A, colptr, esrc, dinv, Bb, n);

    k_pool<<<(n + 63) / 64, 64, 0, stream>>>(Bb, batch, gsum, gcnt, n);
    k_head<<<64, 128, 0, stream>>>(gsum, gcnt, hw1, hb1, hw2, hb2, out);
}

// Round 21
// 279.227 us; speedup vs baseline: 1.0342x; 1.0342x over previous
//
#include <hip/hip_runtime.h>

typedef _Float16 f16;
typedef __attribute__((ext_vector_type(2))) _Float16 f16x2;
typedef __attribute__((ext_vector_type(8))) _Float16 f16x8;
typedef __attribute__((ext_vector_type(4))) float f32x4;
typedef __attribute__((ext_vector_type(2))) float f32x2;

#define BSH 9   // 512 nodes per bucket

// ---------------- fused first kernel: weight conv + zeroing | bucket count | x->fp16 ----------------
__global__ __launch_bounds__(256) void k_wconv(const float* __restrict__ w1, const float* __restrict__ w2,
                                               const float* __restrict__ w3, f16* __restrict__ whi,
                                               f16* __restrict__ wlo, const int* __restrict__ col,
                                               int* __restrict__ bcnt, int* __restrict__ gcnt,
                                               float* __restrict__ gsum, const float* __restrict__ x,
                                               f16* __restrict__ xh, int e, int nx, int nwg_e) {
    int t = threadIdx.x;
    if (blockIdx.x < 192) {
        int tid = blockIdx.x * 256 + t;
        if (tid < 64) gcnt[tid] = 0;
        else if (tid < 64 + 8192) gsum[tid - 64] = 0.f;

        int wsel = blockIdx.x >> 6;
        const float* w = (wsel == 0) ? w1 : (wsel == 1) ? w2 : w3;
        int fi = (blockIdx.x & 63) * 256 + t;   // 0..16383
        int j  = fi & 7;
        int l  = (fi >> 3) & 63;
        int ks = (fi >> 9) & 3;
        int ct = fi >> 11;
        int k = ks * 32 + (l >> 4) * 8 + j;
        int c = ct * 16 + (l & 15);
        float xv = w[k * 128 + c];
        f16 hi = (f16)xv;
        f16 lo = (f16)(xv - (float)hi);
        whi[wsel * 16384 + fi] = hi;
        wlo[wsel * 16384 + fi] = lo;
    } else if (blockIdx.x < 192 + nwg_e) {
        __shared__ int h[256];
        h[t] = 0;
        __syncthreads();
        int bid = blockIdx.x - 192;
        int i0 = bid * 4096;
        int i1 = min(i0 + 4096, e);
        for (int i = i0 + t; i < i1; i += 256) atomicAdd(&h[col[i] >> BSH], 1);
        __syncthreads();
        if (h[t]) atomicAdd(&bcnt[t], h[t]);
    } else {
        long bid = blockIdx.x - 192 - nwg_e;
        long i = bid * 2048 + (long)t * 8;
        if (i + 8 <= nx) {
            float4 a = ((const float4*)(x + i))[0];
            float4 b = ((const float4*)(x + i))[1];
            f16x8 v;
            v[0] = (f16)a.x; v[1] = (f16)a.y; v[2] = (f16)a.z; v[3] = (f16)a.w;
            v[4] = (f16)b.x; v[5] = (f16)b.y; v[6] = (f16)b.z; v[7] = (f16)b.w;
            *(f16x8*)(xh + i) = v;
        } else {
            for (; i < nx; i++) xh[i] = (f16)x[i];
        }
    }
}

// ---------------- bucket scan ----------------
__global__ __launch_bounds__(256) void k_bscan(const int* __restrict__ bcnt, int* __restrict__ bbase,
                                               int* __restrict__ bcur, int* __restrict__ colptr, int e, int n) {
    __shared__ int s[256];
    int t = threadIdx.x;
    int v = bcnt[t];
    s[t] = v;
    __syncthreads();
    for (int off = 1; off < 256; off <<= 1) {
        int mine = s[t];
        int add  = (t >= off) ? s[t - off] : 0;
        __syncthreads();
        s[t] = mine + add;
        __syncthreads();
    }
    int incl = s[t];
    bbase[t + 1] = incl;
    bcur[t] = incl - v;
    if (t == 0) {
        bbase[0] = 0;
        colptr[n] = e;
    }
}

// ---------------- bucket partition ----------------
__global__ __launch_bounds__(256) void k_part(const int* __restrict__ row, const int* __restrict__ col,
                                              int* __restrict__ bcur, int* __restrict__ ebuck, int e) {
    __shared__ int hist[256];
    __shared__ int excl[256];
    __shared__ int rbase[256];
    __shared__ int2 stage[4096];
    int t = threadIdx.x;
    int wgbase = blockIdx.x * 4096;
    int total = min(4096, e - wgbase);

    hist[t] = 0;
    __syncthreads();

    int  mypk[16];
    int  myb[16];
    int  myrank[16];
    #pragma unroll
    for (int k = 0; k < 16; k++) {
        int i = wgbase + k * 256 + t;
        int pk = 0, b = 0, rnk = 0;
        if (i < e) {
            int r = row[i];
            int c = col[i];
            b = c >> BSH;
            pk = (r << BSH) | (c & ((1 << BSH) - 1));
            rnk = atomicAdd(&hist[b], 1);
        }
        mypk[k] = pk;
        myb[k] = b;
        myrank[k] = rnk;
    }
    __syncthreads();

    excl[t] = hist[t];
    __syncthreads();
    for (int off = 1; off < 256; off <<= 1) {
        int mine = excl[t];
        int add  = (t >= off) ? excl[t - off] : 0;
        __syncthreads();
        excl[t] = mine + add;
        __syncthreads();
    }
    excl[t] -= hist[t];
    rbase[t] = (hist[t] > 0) ? atomicAdd(&bcur[t], hist[t]) : 0;
    __syncthreads();

    #pragma unroll
    for (int k = 0; k < 16; k++) {
        int i = wgbase + k * 256 + t;
        if (i < e) stage[excl[myb[k]] + myrank[k]] = make_int2(mypk[k], myb[k]);
    }
    __syncthreads();

    for (int j = t; j < total; j += 256) {
        int2 pe = stage[j];
        int b = pe.y;
        ebuck[rbase[b] + (j - excl[b])] = pe.x;
    }
}

// ---------------- per-bucket: histogram + scan -> colptr/dinv, scatter esrc via LDS cursors ----------------
__global__ __launch_bounds__(256) void k_nodefill(const int* __restrict__ ebuck, const int* __restrict__ bbase,
                                                  int* __restrict__ colptr, float* __restrict__ dinv,
                                                  int* __restrict__ esrc, int n) {
    __shared__ int h[512];
    __shared__ int s[256];
    __shared__ int cur[512];
    int b = blockIdx.x;
    int t = threadIdx.x;
    h[t] = 0;
    h[t + 256] = 0;
    __syncthreads();
    int e_lo = bbase[b], e_hi = bbase[b + 1];
    for (int i = e_lo + t; i < e_hi; i += 256) atomicAdd(&h[ebuck[i] & 511], 1);
    __syncthreads();
    int a0 = h[2 * t], a1 = h[2 * t + 1];
    s[t] = a0 + a1;
    __syncthreads();
    for (int off = 1; off < 256; off <<= 1) {
        int mine = s[t];
        int add  = (t >= off) ? s[t - off] : 0;
        __syncthreads();
        s[t] = mine + add;
        __syncthreads();
    }
    int sexcl = s[t] - (a0 + a1);
    int g0 = (b << BSH) + 2 * t;
    int g1 = g0 + 1;
    int cp0 = e_lo + sexcl;
    int cp1 = cp0 + a0;
    if (g0 < n) {
        colptr[g0] = cp0;
        dinv[g0] = rsqrtf((float)(a0 + 1));
    }
    if (g1 < n) {
        colptr[g1] = cp1;
        dinv[g1] = rsqrtf((float)(a1 + 1));
    }
    cur[2 * t]     = cp0;
    cur[2 * t + 1] = cp1;
    __syncthreads();
    for (int i = e_lo + t; i < e_hi; i += 256) {
        int pk = ebuck[i];
        int pos = atomicAdd(&cur[pk & 511], 1);
        esrc[pos] = pk >> BSH;
    }
}

__device__ __forceinline__ unsigned char f32_to_fp8(float v) {
    int pk = __builtin_amdgcn_cvt_pk_fp8_f32(v, v, 0, 0);
    return (unsigned char)(pk & 0xff);
}

// ---------------- GEMM (fp16 input, all 3 layers): A[r] = fp8(dinv[r] * (in[r] @ W + b)) ----------------
// 64-row blocks; LDS-staged fp8 epilogue: byte-writes to an 8 KB tile, then coalesced uint4 stores.
__global__ __launch_bounds__(256) void k_gemm_f16in(const f16* __restrict__ in, const f16* __restrict__ whi,
                                                    const f16* __restrict__ wlo, const float* __restrict__ bias,
                                                    const float* __restrict__ dinv, unsigned char* __restrict__ out,
                                                    int n) {
    __shared__ unsigned char ot[64 * 128];
    int lane = threadIdx.x & 63;
    int wid  = threadIdx.x >> 6;
    int wr = wid >> 1, wc = wid & 1;
    int rbase0 = blockIdx.x * 64;
    int rbase = rbase0 + wr * 32;
    int rowA = lane & 15;
    int kg   = lane >> 4;

    f32x4 acc[2][4];
    #pragma unroll
    for (int i = 0; i < 2; i++)
        #pragma unroll
        for (int j = 0; j < 4; j++) acc[i][j] = (f32x4){0.f, 0.f, 0.f, 0.f};

    #pragma unroll
    for (int ks = 0; ks < 4; ks++) {
        f16x8 ah[2];
        #pragma unroll
        for (int rt = 0; rt < 2; rt++) {
            int r = rbase + rt * 16 + rowA;
            int k0 = ks * 32 + kg * 8;
            f16x8 v = {};
            if (r < n) v = *(const f16x8*)(in + (size_t)r * 128 + k0);
            ah[rt] = v;
        }
        f16x8 bh[4], bl[4];
        #pragma unroll
        for (int ct = 0; ct < 4; ct++) {
            int g = ((wc * 4 + ct) * 4 + ks);
            size_t idx = (size_t)(g * 64 + lane) * 8;
            bh[ct] = *(const f16x8*)(whi + idx);
            bl[ct] = *(const f16x8*)(wlo + idx);
        }
        #pragma unroll
        for (int rt = 0; rt < 2; rt++)
            #pragma unroll
            for (int ct = 0; ct < 4; ct++) {
                acc[rt][ct] = __builtin_amdgcn_mfma_f32_16x16x32_f16(ah[rt], bl[ct], acc[rt][ct], 0, 0, 0);
                acc[rt][ct] = __builtin_amdgcn_mfma_f32_16x16x32_f16(ah[rt], bh[ct], acc[rt][ct], 0, 0, 0);
            }
    }

    int cl = lane & 15;
    int rq = lane >> 4;
    #pragma unroll
    for (int rt = 0; rt < 2; rt++) {
        #pragma unroll
        for (int ct = 0; ct < 4; ct++) {
            int c = wc * 64 + ct * 16 + cl;
            float bv = bias[c];
            #pragma unroll
            for (int reg = 0; reg < 4; reg++) {
                int rl = wr * 32 + rt * 16 + rq * 4 + reg;
                int r = rbase0 + rl;
                if (r < n) {
                    float dv = dinv[r];
                    ot[rl * 128 + c] = f32_to_fp8(dv * (acc[rt][ct][reg] + bv));
                }
            }
        }
    }
    __syncthreads();

    int rows = min(64, n - rbase0);
    uint4* dst = (uint4*)(out + (size_t)rbase0 * 128);
    const uint4* src = (const uint4*)ot;
    for (int idx = threadIdx.x; idx < rows * 8; idx += 256) dst[idx] = src[idx];
}

// ---------------- Aggregation v6-fp8: 2 nodes/wave, 16 B/lane uint4 loads, 8-slot stepping ----------------
__global__ __launch_bounds__(256) void k_agg(const unsigned char* __restrict__ A, const int* __restrict__ colptr,
                                             const int* __restrict__ esrc, const float* __restrict__ dinv,
                                             f16* __restrict__ B, int n) {
    int lane = threadIdx.x & 63;
    int half = lane >> 5;
    int l = lane & 31;
    int eg = l >> 3;     // 0..3
    int cs = l & 7;      // 0..7
    int v = blockIdx.x * 8 + (threadIdx.x >> 6) * 2 + half;
    const uint4* __restrict__ A16 = (const uint4*)A;

    int p0 = 0, total = 0;
    if (v < n) {
        p0 = colptr[v];
        int p1 = colptr[v + 1];
        total = p1 - p0 + 1;
    }

    f32x2 acc2[8];
    #pragma unroll
    for (int j = 0; j < 8; j++) acc2[j] = (f32x2){0.f, 0.f};

    for (int base = 0; base < total; base += 8) {
        int q0 = base + eg;
        int q1 = base + 4 + eg;
        int s0 = (q0 < total - 1) ? esrc[p0 + q0] : v;
        int s1 = (q1 < total - 1) ? esrc[p0 + q1] : v;
        uint4 r0 = A16[(size_t)s0 * 8 + cs];
        uint4 r1 = A16[(size_t)s1 * 8 + cs];
        float m0 = (q0 < total) ? 1.f : 0.f;
        float m1 = (q1 < total) ? 1.f : 0.f;
        f32x2 m0v = (f32x2){m0, m0};
        f32x2 m1v = (f32x2){m1, m1};
        acc2[0] = __builtin_amdgcn_cvt_pk_f32_fp8((int)r0.x, false) * m0v + acc2[0];
        acc2[1] = __builtin_amdgcn_cvt_pk_f32_fp8((int)r0.x, true)  * m0v + acc2[1];
        acc2[2] = __builtin_amdgcn_cvt_pk_f32_fp8((int)r0.y, false) * m0v + acc2[2];
        acc2[3] = __builtin_amdgcn_cvt_pk_f32_fp8((int)r0.y, true)  * m0v + acc2[3];
        acc2[4] = __builtin_amdgcn_cvt_pk_f32_fp8((int)r0.z, false) * m0v + acc2[4];
        acc2[5] = __builtin_amdgcn_cvt_pk_f32_fp8((int)r0.z, true)  * m0v + acc2[5];
        acc2[6] = __builtin_amdgcn_cvt_pk_f32_fp8((int)r0.w, false) * m0v + acc2[6];
        acc2[7] = __builtin_amdgcn_cvt_pk_f32_fp8((int)r0.w, true)  * m0v + acc2[7];
        acc2[0] = __builtin_amdgcn_cvt_pk_f32_fp8((int)r1.x, false) * m1v + acc2[0];
        acc2[1] = __builtin_amdgcn_cvt_pk_f32_fp8((int)r1.x, true)  * m1v + acc2[1];
        acc2[2] = __builtin_amdgcn_cvt_pk_f32_fp8((int)r1.y, false) * m1v + acc2[2];
        acc2[3] = __builtin_amdgcn_cvt_pk_f32_fp8((int)r1.y, true)  * m1v + acc2[3];
        acc2[4] = __builtin_amdgcn_cvt_pk_f32_fp8((int)r1.z, false) * m1v + acc2[4];
        acc2[5] = __builtin_amdgcn_cvt_pk_f32_fp8((int)r1.z, true)  * m1v + acc2[5];
        acc2[6] = __builtin_amdgcn_cvt_pk_f32_fp8((int)r1.w, false) * m1v + acc2[6];
        acc2[7] = __builtin_amdgcn_cvt_pk_f32_fp8((int)r1.w, true)  * m1v + acc2[7];
    }

    float accf[16];
    #pragma unroll
    for (int j = 0; j < 8; j++) {
        #pragma unroll
        for (int h = 0; h < 2; h++) {
            float a = acc2[j][h];
            a += __shfl_xor(a, 8, 64);
            a += __shfl_xor(a, 16, 64);
            accf[2 * j + h] = a;
        }
    }

    if (v < n && l < 8) {
        float d = dinv[v];
        f16x8 o0, o1;
        #pragma unroll
        for (int j = 0; j < 8; j++) {
            o0[j] = (f16)fmaxf(d * accf[j], 0.f);
            o1[j] = (f16)fmaxf(d * accf[8 + j], 0.f);
        }
        f16x8* Bp = (f16x8*)(B + (size_t)v * 128 + cs * 16);
        Bp[0] = o0;
        Bp[1] = o1;
    }
}

// ---------------- Pooling (batch is sorted), B fp16, f16x2 per lane ----------------
__global__ __launch_bounds__(64) void k_pool(const f16* __restrict__ B, const int* __restrict__ batch,
                                             float* __restrict__ gsum, int* __restrict__ gcnt, int n) {
    int c = threadIdx.x;
    int base = blockIdx.x * 64;
    if (base >= n) return;
    int end = min(base + 64, n);
    int curg = batch[base];
    const f16x2* __restrict__ B2 = (const f16x2*)B;
    float ax = 0.f, ay = 0.f;
    int cnt = 0;
    for (int i = base; i < end; i++) {
        int g = batch[i];
        if (g != curg) {
            atomicAdd(&gsum[curg * 128 + 2 * c], ax);
            atomicAdd(&gsum[curg * 128 + 2 * c + 1], ay);
            if (c == 0) atomicAdd(&gcnt[curg], cnt);
            ax = ay = 0.f; cnt = 0; curg = g;
        }
        f16x2 v = B2[(size_t)i * 64 + c];
        ax += (float)v.x;
        ay += (float)v.y;
        cnt++;
    }
    atomicAdd(&gsum[curg * 128 + 2 * c], ax);
    atomicAdd(&gsum[curg * 128 + 2 * c + 1], ay);
    if (c == 0) atomicAdd(&gcnt[curg], cnt);
}

// ---------------- Head ----------------
__global__ __launch_bounds__(128) void k_head(const float* __restrict__ gsum, const int* __restrict__ gcnt,
                                              const float* __restrict__ hw1, const float* __restrict__ hb1,
                                              const float* __restrict__ hw2, const float* __restrict__ hb2,
                                              float* __restrict__ out) {
    __shared__ float mean[128];
    __shared__ float red[128];
    int g = blockIdx.x;
    int c = threadIdx.x;
    float cntf = fmaxf((float)gcnt[g], 1.0f);
    mean[c] = gsum[g * 128 + c] / cntf;
    __syncthreads();
    float h = hb1[c];
    for (int k = 0; k < 128; k++) h = fmaf(mean[k], hw1[k * 128 + c], h);
    h = fmaxf(h, 0.f);
    red[c] = h * hw2[c];
    __syncthreads();
    for (int s = 64; s > 0; s >>= 1) {
        if (c < s) red[c] += red[c + s];
        __syncthreads();
    }
    if (c == 0) out[g] = red[0] + hb2[0];
}

// ---------------- launch ----------------
extern "C" void kernel_launch(void* const* d_in, const int* in_sizes, int n_in,
                              void* d_out, int out_size, void* d_ws, size_t ws_size,
                              hipStream_t stream) {
    const float* x   = (const float*)d_in[0];
    const int*  edge = (const int*)d_in[1];
    const int*  batch= (const int*)d_in[2];
    const float* w1  = (const float*)d_in[3];
    const float* b1  = (const float*)d_in[4];
    const float* w2  = (const float*)d_in[5];
    const float* b2  = (const float*)d_in[6];
    const float* w3  = (const float*)d_in[7];
    const float* b3  = (const float*)d_in[8];
    const float* hw1 = (const float*)d_in[9];
    const float* hb1 = (const float*)d_in[10];
    const float* hw2 = (const float*)d_in[11];
    const float* hb2 = (const float*)d_in[12];
    float* out = (float*)d_out;

    const int n = in_sizes[0] / 128;
    const int e = in_sizes[1] / 2;
    const int* row = edge;
    const int* col = edge + e;

    char* wsb = (char*)d_ws;
    size_t off = 0;
    auto alloc = [&](size_t bytes) -> void* {
        void* p = wsb + off;
        off = (off + bytes + 511) & ~size_t(511);
        return p;
    };
    unsigned char* A = (unsigned char*)alloc((size_t)n * 128);   // fp8 activations (gemm out, gathered)
    f16*   Bb     = (f16*)  alloc((size_t)n * 128 * 2);          // fp16 activations (agg out)
    f16*   xh     = (f16*)  alloc((size_t)n * 128 * 2);          // fp16 copy of x
    int*   ebuck  = (int*)  alloc((size_t)e * 4);
    float* dinv   = (float*)alloc((size_t)n * 4);
    int*   colptr = (int*)  alloc((size_t)(n + 1) * 4);
    int*   bcnt   = (int*)  alloc(1024);
    int*   bbase  = (int*)  alloc(1028 + 508);
    int*   bcur   = (int*)  alloc(1024);
    int*   esrc   = (int*)  alloc((size_t)e * 4);
    float* gsum   = (float*)alloc(64 * 128 * 4);
    int*   gcnt   = (int*)  alloc(64 * 4);
    f16*   whi    = (f16*)  alloc(3 * 16384 * 2);
    f16*   wlo    = (f16*)  alloc(3 * 16384 * 2);

    hipMemsetAsync(bcnt, 0, 1024, stream);

    int nwg_e = (e + 4095) / 4096;
    int nwg_x = (n * 128 + 2047) / 2048;
    int nbk = (n + (1 << BSH) - 1) >> BSH;

    // fused: weight conv + zeroing | bucket count | x->fp16
    k_wconv<<<192 + nwg_e + nwg_x, 256, 0, stream>>>(w1, w2, w3, whi, wlo, col, bcnt, gcnt, gsum,
                                                     x, xh, e, n * 128, nwg_e);

    k_bscan<<<1, 256, 0, stream>>>(bcnt, bbase, bcur, colptr, e, n);
    k_part<<<nwg_e, 256, 0, stream>>>(row, col, bcur, ebuck, e);
    k_nodefill<<<nbk, 256, 0, stream>>>(ebuck, bbase, colptr, dinv, esrc, n);

    int gb = (n + 63) / 64;
    int ab = (n + 7) / 8;
    k_gemm_f16in<<<gb, 256, 0, stream>>>(xh, whi,             wlo,             b1, dinv, A, n);
    k_agg <<<ab, 256, 0, stream>>>(A, colptr, esrc, dinv, Bb, n);
    k_gemm_f16in<<<gb, 256, 0, stream>>>(Bb, whi + 16384,     wlo + 16384,     b2, dinv, A, n);
    k_agg <<<ab, 256, 0, stream>>>(A, colptr, esrc, dinv, Bb, n);
    k_gemm_f16in<<<gb, 256, 0, stream>>>(Bb, whi + 2 * 16384, wlo + 2 * 16384, b3, dinv, A, n);
    k_agg <<<ab, 256, 0, stream>>>(A, colptr, esrc, dinv, Bb, n);

    k_pool<<<(n + 63) / 64, 64, 0, stream>>>(Bb, batch, gsum, gcnt, n);
    k_head<<<64, 128, 0, stream>>>(gsum, gcnt, hw1, hb1, hw2, hb2, out);
}